// Round 1
// baseline (3027.894 us; speedup 1.0000x reference)
//
#include <hip/hip_runtime.h>

#define N_NODES 100000
#define DIM 128

// ---------------- counts (degree per edge type) ----------------
__global__ void count_kernel(const int* __restrict__ idx1, int ngroups, int arity,
                             int* __restrict__ counts) {
    int g = blockIdx.x * 256 + threadIdx.x;
    if (g < ngroups) {
        atomicAdd(&counts[idx1[g * arity]], 1);
    }
}

// ---------------- C_w transpose: CwT[k][o] = Cw[o][k] ----------------
__global__ void transpose_cw_kernel(const float* __restrict__ Cw, float* __restrict__ CwT) {
    int o = blockIdx.x;   // 128 blocks
    int k = threadIdx.x;  // 128 threads
    CwT[k * DIM + o] = Cw[o * DIM + k];
}

// ---------------- main tiled matmul ----------------
// MODE 0: edge-type message kernel — gather src rows via idx0, multiply by B=[128*ARITY][128],
//         scale by 1/counts[dest], atomicAdd into out[dest].
// MODE 1: dense kernel — out[g] = x[g] @ B + bias (direct store; B = CwT).
template <int ARITY, int MODE>
__global__ __launch_bounds__(256, 2) void hgnn_mm_kernel(
    const float* __restrict__ x,
    const int* __restrict__ idx0,
    const int* __restrict__ idx1,
    const float* __restrict__ B,      // [128*ARITY][128] row-major
    const int* __restrict__ counts,   // MODE 0 only
    const float* __restrict__ bias,   // MODE 1 only
    float* __restrict__ out,
    int ngroups)
{
    constexpr int BG = 128;   // groups per block
    constexpr int KC = 32;    // K-chunk
    constexpr int SP = 132;   // S row stride (floats), 16B-aligned rows

    __shared__ float Sh[KC][SP];    // S^T chunk: Sh[kk][g_local]
    __shared__ float Ah[KC][DIM];   // B chunk:   Ah[kk][col]
    __shared__ int nodebuf[BG];

    const int tid = threadIdx.x;
    const int g0 = blockIdx.x * BG;
    const int tc = tid >> 4;   // 0..15 : col block of 8
    const int tg = tid & 15;   // 0..15 : group block of 8

    float acc[8][8];
#pragma unroll
    for (int i = 0; i < 8; ++i)
#pragma unroll
        for (int j = 0; j < 8; ++j) acc[i][j] = 0.f;

    for (int a = 0; a < ARITY; ++a) {
        __syncthreads();
        if (tid < BG) {
            int g = g0 + tid;
            int node = 0;
            if (g < ngroups) node = (MODE == 1) ? g : idx0[g * ARITY + a];
            nodebuf[tid] = node;
        }
        __syncthreads();

        for (int f0 = 0; f0 < DIM; f0 += KC) {
            const int k0 = a * DIM + f0;
            // stage B chunk: rows k0..k0+31, 128 cols = 1024 float4, straight copy
            {
                const float4* Bv = reinterpret_cast<const float4*>(B + (size_t)k0 * DIM);
                float4* Av = reinterpret_cast<float4*>(&Ah[0][0]);
#pragma unroll
                for (int i = 0; i < 4; ++i) Av[tid + i * 256] = Bv[tid + i * 256];
            }
            // stage S chunk (transposed): 128 groups x 32 feats = 1024 float4 gathered
#pragma unroll
            for (int i = 0; i < 4; ++i) {
                int item = tid + i * 256;  // 0..1023
                int g = item >> 3;         // 0..127 group local
                int q = item & 7;          // float4 slot within 32 feats
                const float4* xv =
                    reinterpret_cast<const float4*>(x + (size_t)nodebuf[g] * DIM + f0) + q;
                float4 v = *xv;
                Sh[q * 4 + 0][g] = v.x;
                Sh[q * 4 + 1][g] = v.y;
                Sh[q * 4 + 2][g] = v.z;
                Sh[q * 4 + 3][g] = v.w;
            }
            __syncthreads();

#pragma unroll
            for (int kk = 0; kk < KC; ++kk) {
                float4 s0 = *reinterpret_cast<const float4*>(&Sh[kk][tg * 8]);
                float4 s1 = *reinterpret_cast<const float4*>(&Sh[kk][tg * 8 + 4]);
                float4 a0 = *reinterpret_cast<const float4*>(&Ah[kk][tc * 8]);
                float4 a1 = *reinterpret_cast<const float4*>(&Ah[kk][tc * 8 + 4]);
                float sv[8] = {s0.x, s0.y, s0.z, s0.w, s1.x, s1.y, s1.z, s1.w};
                float av[8] = {a0.x, a0.y, a0.z, a0.w, a1.x, a1.y, a1.z, a1.w};
#pragma unroll
                for (int gi = 0; gi < 8; ++gi)
#pragma unroll
                    for (int ci = 0; ci < 8; ++ci) acc[gi][ci] += sv[gi] * av[ci];
            }
            __syncthreads();
        }
    }

    if (MODE == 1) {
        float bv[8];
#pragma unroll
        for (int ci = 0; ci < 8; ++ci) bv[ci] = bias[tc * 8 + ci];
#pragma unroll
        for (int gi = 0; gi < 8; ++gi) {
            int g = g0 + tg * 8 + gi;
            if (g < ngroups) {
                float4 o0, o1;
                o0.x = acc[gi][0] + bv[0];
                o0.y = acc[gi][1] + bv[1];
                o0.z = acc[gi][2] + bv[2];
                o0.w = acc[gi][3] + bv[3];
                o1.x = acc[gi][4] + bv[4];
                o1.y = acc[gi][5] + bv[5];
                o1.z = acc[gi][6] + bv[6];
                o1.w = acc[gi][7] + bv[7];
                float* op = out + (size_t)g * DIM + tc * 8;
                *reinterpret_cast<float4*>(op) = o0;
                *reinterpret_cast<float4*>(op + 4) = o1;
            }
        }
    } else {
#pragma unroll
        for (int gi = 0; gi < 8; ++gi) {
            int g = g0 + tg * 8 + gi;
            if (g < ngroups) {
                int dest = idx1[g * ARITY];
                float inv = 1.0f / (float)counts[dest];
                float* op = out + (size_t)dest * DIM + tc * 8;
#pragma unroll
                for (int ci = 0; ci < 8; ++ci) {
                    __hip_atomic_fetch_add(&op[ci], acc[gi][ci] * inv,
                                           __ATOMIC_RELAXED, __HIP_MEMORY_SCOPE_AGENT);
                }
            }
        }
    }
}

extern "C" void kernel_launch(void* const* d_in, const int* in_sizes, int n_in,
                              void* d_out, int out_size, void* d_ws, size_t ws_size,
                              hipStream_t stream) {
    const float* x  = (const float*)d_in[0];
    const int*   e1 = (const int*)d_in[1];
    const int*   e2 = (const int*)d_in[2];
    const int*   e3 = (const int*)d_in[3];
    const float* A1 = (const float*)d_in[4];
    const float* A2 = (const float*)d_in[5];
    const float* A3 = (const float*)d_in[6];
    const float* Cw = (const float*)d_in[7];
    const float* Cb = (const float*)d_in[8];
    float* out = (float*)d_out;

    const int ne1 = in_sizes[1] / 2;  // 300000 entries per row
    const int ne2 = in_sizes[2] / 2;  // 600000
    const int ne3 = in_sizes[3] / 2;  // 600000
    const int ng1 = ne1 / 1;          // 300000 groups
    const int ng2 = ne2 / 2;          // 300000
    const int ng3 = ne3 / 3;          // 200000

    int* counts1 = (int*)d_ws;
    int* counts2 = counts1 + N_NODES;
    int* counts3 = counts2 + N_NODES;
    float* CwT   = (float*)(counts3 + N_NODES);

    hipMemsetAsync(d_ws, 0, 3 * N_NODES * sizeof(int), stream);
    transpose_cw_kernel<<<DIM, DIM, 0, stream>>>(Cw, CwT);
    count_kernel<<<(ng1 + 255) / 256, 256, 0, stream>>>(e1 + ne1, ng1, 1, counts1);
    count_kernel<<<(ng2 + 255) / 256, 256, 0, stream>>>(e2 + ne2, ng2, 2, counts2);
    count_kernel<<<(ng3 + 255) / 256, 256, 0, stream>>>(e3 + ne3, ng3, 3, counts3);

    // dense: out = x @ Cw^T + Cb  (writes every row -> initializes d_out)
    hgnn_mm_kernel<1, 1><<<(N_NODES + 127) / 128, 256, 0, stream>>>(
        x, nullptr, nullptr, CwT, nullptr, Cb, out, N_NODES);
    // edge types: atomicAdd normalized messages on top
    hgnn_mm_kernel<1, 0><<<(ng1 + 127) / 128, 256, 0, stream>>>(
        x, e1, e1 + ne1, A1, counts1, nullptr, out, ng1);
    hgnn_mm_kernel<2, 0><<<(ng2 + 127) / 128, 256, 0, stream>>>(
        x, e2, e2 + ne2, A2, counts2, nullptr, out, ng2);
    hgnn_mm_kernel<3, 0><<<(ng3 + 127) / 128, 256, 0, stream>>>(
        x, e3, e3 + ne3, A3, counts3, nullptr, out, ng3);
}

// Round 2
// 1076.709 us; speedup vs baseline: 2.8122x; 2.8122x over previous
//
#include <hip/hip_runtime.h>

#define N_NODES 100000
#define DIM 128

// ---------------- counts (degree per edge type) ----------------
__global__ void count_kernel(const int* __restrict__ idx1, int ngroups, int arity,
                             int* __restrict__ counts) {
    int g = blockIdx.x * 256 + threadIdx.x;
    if (g < ngroups) {
        atomicAdd(&counts[idx1[g * arity]], 1);
    }
}

// ---------------- exclusive prefix scan (single block, 1024 thr, 4 elem/thr) ----
__global__ __launch_bounds__(1024) void scan_kernel(const int* __restrict__ counts,
                                                    int* __restrict__ cursor, int n) {
    __shared__ int buf[1024];
    __shared__ int carry_s;
    const int tid = threadIdx.x;
    if (tid == 0) carry_s = 0;
    __syncthreads();
    for (int base = 0; base < n; base += 4096) {
        int v[4];
        int s = 0;
#pragma unroll
        for (int i = 0; i < 4; ++i) {
            int idx = base + tid * 4 + i;
            v[i] = (idx < n) ? counts[idx] : 0;
            s += v[i];
        }
        buf[tid] = s;
        __syncthreads();
        for (int off = 1; off < 1024; off <<= 1) {
            int t = (tid >= off) ? buf[tid - off] : 0;
            __syncthreads();
            buf[tid] += t;
            __syncthreads();
        }
        int incl = buf[tid];
        int carry = carry_s;
        int run = incl - s + carry;  // exclusive prefix of this thread's first elem
#pragma unroll
        for (int i = 0; i < 4; ++i) {
            int idx = base + tid * 4 + i;
            if (idx < n) cursor[idx] = run;
            run += v[i];
        }
        __syncthreads();
        if (tid == 1023) carry_s = carry + incl;  // add chunk total
        __syncthreads();
    }
}

// ---------------- counting-sort scatter: sorted[] = group ids ordered by dest ----
__global__ void scatter_kernel(const int* __restrict__ idx1, int* __restrict__ cursor,
                               int* __restrict__ sorted, int ngroups, int arity) {
    int g = blockIdx.x * 256 + threadIdx.x;
    if (g < ngroups) {
        int d = idx1[g * arity];
        int pos = atomicAdd(&cursor[d], 1);
        sorted[pos] = g;
    }
}

// ---------------- C_w transpose: CwT[k][o] = Cw[o][k] ----------------
__global__ void transpose_cw_kernel(const float* __restrict__ Cw, float* __restrict__ CwT) {
    int o = blockIdx.x;   // 128 blocks
    int k = threadIdx.x;  // 128 threads
    CwT[k * DIM + o] = Cw[o * DIM + k];
}

// ---------------- main tiled matmul ----------------
// MODE 0: edge-type message kernel over groups in sorted-by-dest order;
//         segmented epilogue flushes one contiguous atomic row per dest-run.
// MODE 1: dense kernel — out[g] = x[g] @ B + bias (direct store; B = CwT).
template <int ARITY, int MODE>
__global__ __launch_bounds__(256, 4) void hgnn_mm_kernel(
    const float* __restrict__ x,
    const int* __restrict__ idx0,
    const int* __restrict__ idx1,
    const int* __restrict__ sorted,   // MODE 0 only
    const float* __restrict__ B,      // [128*ARITY][128] row-major
    const int* __restrict__ counts,   // MODE 0 only
    const float* __restrict__ bias,   // MODE 1 only
    float* __restrict__ out,
    int ngroups)
{
    constexpr int BG = 128;   // groups per block
    constexpr int KC = 32;    // K-chunk
    constexpr int SP = 132;   // S row stride (floats)

    __shared__ float Sh[KC][SP];    // S^T chunk: Sh[kk][g_local]; reused as epilogue stage
    __shared__ float Ah[KC][DIM];   // B chunk:   Ah[kk][col]
    __shared__ int nodebuf[BG];
    __shared__ int sgidbuf[BG];
    __shared__ int destbuf[BG];
    __shared__ float invbuf[BG];

    const int tid = threadIdx.x;
    const int g0 = blockIdx.x * BG;
    const int tc = tid >> 4;   // 0..15 : col block of 8
    const int tg = tid & 15;   // 0..15 : group block of 8

    if (MODE == 0) {
        if (tid < BG) {
            int g = g0 + tid;
            int sg = (g < ngroups) ? sorted[g] : 0;
            sgidbuf[tid] = sg;  // read back only by same thread before sync; others after sync
            int d = (g < ngroups) ? idx1[sg * ARITY] : -1;
            destbuf[tid] = d;
            invbuf[tid] = (g < ngroups) ? (1.0f / (float)counts[d]) : 0.f;
        }
    }

    float acc[8][8];
#pragma unroll
    for (int i = 0; i < 8; ++i)
#pragma unroll
        for (int j = 0; j < 8; ++j) acc[i][j] = 0.f;

    for (int a = 0; a < ARITY; ++a) {
        __syncthreads();
        if (tid < BG) {
            int g = g0 + tid;
            int node = 0;
            if (g < ngroups) node = (MODE == 1) ? g : idx0[sgidbuf[tid] * ARITY + a];
            nodebuf[tid] = node;
        }
        __syncthreads();

        for (int f0 = 0; f0 < DIM; f0 += KC) {
            const int k0 = a * DIM + f0;
            // stage B chunk: rows k0..k0+31, 128 cols = 1024 float4
            {
                const float4* Bv = reinterpret_cast<const float4*>(B + (size_t)k0 * DIM);
                float4* Av = reinterpret_cast<float4*>(&Ah[0][0]);
#pragma unroll
                for (int i = 0; i < 4; ++i) Av[tid + i * 256] = Bv[tid + i * 256];
            }
            // stage S chunk (transposed): 128 groups x 32 feats gathered
#pragma unroll
            for (int i = 0; i < 4; ++i) {
                int item = tid + i * 256;  // 0..1023
                int g = item >> 3;         // group local
                int q = item & 7;          // float4 slot
                const float4* xv =
                    reinterpret_cast<const float4*>(x + (size_t)nodebuf[g] * DIM + f0) + q;
                float4 v = *xv;
                Sh[q * 4 + 0][g] = v.x;
                Sh[q * 4 + 1][g] = v.y;
                Sh[q * 4 + 2][g] = v.z;
                Sh[q * 4 + 3][g] = v.w;
            }
            __syncthreads();

#pragma unroll
            for (int kk = 0; kk < KC; ++kk) {
                float4 s0 = *reinterpret_cast<const float4*>(&Sh[kk][tg * 8]);
                float4 s1 = *reinterpret_cast<const float4*>(&Sh[kk][tg * 8 + 4]);
                float4 a0 = *reinterpret_cast<const float4*>(&Ah[kk][tc * 8]);
                float4 a1 = *reinterpret_cast<const float4*>(&Ah[kk][tc * 8 + 4]);
                float sv[8] = {s0.x, s0.y, s0.z, s0.w, s1.x, s1.y, s1.z, s1.w};
                float av[8] = {a0.x, a0.y, a0.z, a0.w, a1.x, a1.y, a1.z, a1.w};
#pragma unroll
                for (int gi = 0; gi < 8; ++gi)
#pragma unroll
                    for (int ci = 0; ci < 8; ++ci) acc[gi][ci] += sv[gi] * av[ci];
            }
            __syncthreads();
        }
    }

    if (MODE == 1) {
        float bv[8];
#pragma unroll
        for (int ci = 0; ci < 8; ++ci) bv[ci] = bias[tc * 8 + ci];
#pragma unroll
        for (int gi = 0; gi < 8; ++gi) {
            int g = g0 + tg * 8 + gi;
            if (g < ngroups) {
                float4 o0, o1;
                o0.x = acc[gi][0] + bv[0];
                o0.y = acc[gi][1] + bv[1];
                o0.z = acc[gi][2] + bv[2];
                o0.w = acc[gi][3] + bv[3];
                o1.x = acc[gi][4] + bv[4];
                o1.y = acc[gi][5] + bv[5];
                o1.z = acc[gi][6] + bv[6];
                o1.w = acc[gi][7] + bv[7];
                float* op = out + (size_t)g * DIM + tc * 8;
                *reinterpret_cast<float4*>(op) = o0;
                *reinterpret_cast<float4*>(op + 4) = o1;
            }
        }
    } else {
        // segmented epilogue: stage 32 rows at a time into Sh, each wave walks 8
        // consecutive sorted rows accumulating equal-dest runs, flushes one
        // lane-contiguous atomic row per run.
        const int w = tid >> 6;     // wave 0..3
        const int lane = tid & 63;
        for (int c0 = 0; c0 < BG; c0 += 32) {
            __syncthreads();
            const int tg0 = c0 >> 3;
            if (tg >= tg0 && tg < tg0 + 4) {
#pragma unroll
                for (int gi = 0; gi < 8; ++gi) {
                    int row = ((tg - tg0) << 3) + gi;
#pragma unroll
                    for (int ci = 0; ci < 8; ++ci) Sh[row][tc * 8 + ci] = acc[gi][ci];
                }
            }
            __syncthreads();
            int cur = -1;
            float r0 = 0.f, r1 = 0.f;
#pragma unroll
            for (int r = 0; r < 8; ++r) {
                int row = (w << 3) + r;
                int g = g0 + c0 + row;
                if (g < ngroups) {
                    int d = destbuf[c0 + row];       // uniform across wave
                    float inv = invbuf[c0 + row];
                    if (d != cur) {
                        if (cur >= 0) {
                            float* op = out + (size_t)cur * DIM;
                            __hip_atomic_fetch_add(&op[lane], r0, __ATOMIC_RELAXED,
                                                   __HIP_MEMORY_SCOPE_AGENT);
                            __hip_atomic_fetch_add(&op[lane + 64], r1, __ATOMIC_RELAXED,
                                                   __HIP_MEMORY_SCOPE_AGENT);
                        }
                        cur = d;
                        r0 = 0.f;
                        r1 = 0.f;
                    }
                    r0 += Sh[row][lane] * inv;
                    r1 += Sh[row][lane + 64] * inv;
                }
            }
            if (cur >= 0) {
                float* op = out + (size_t)cur * DIM;
                __hip_atomic_fetch_add(&op[lane], r0, __ATOMIC_RELAXED,
                                       __HIP_MEMORY_SCOPE_AGENT);
                __hip_atomic_fetch_add(&op[lane + 64], r1, __ATOMIC_RELAXED,
                                       __HIP_MEMORY_SCOPE_AGENT);
            }
        }
    }
}

extern "C" void kernel_launch(void* const* d_in, const int* in_sizes, int n_in,
                              void* d_out, int out_size, void* d_ws, size_t ws_size,
                              hipStream_t stream) {
    const float* x  = (const float*)d_in[0];
    const int*   e1 = (const int*)d_in[1];
    const int*   e2 = (const int*)d_in[2];
    const int*   e3 = (const int*)d_in[3];
    const float* A1 = (const float*)d_in[4];
    const float* A2 = (const float*)d_in[5];
    const float* A3 = (const float*)d_in[6];
    const float* Cw = (const float*)d_in[7];
    const float* Cb = (const float*)d_in[8];
    float* out = (float*)d_out;

    const int ne1 = in_sizes[1] / 2;  // 300000 entries per row
    const int ne2 = in_sizes[2] / 2;  // 600000
    const int ne3 = in_sizes[3] / 2;  // 600000
    const int ng1 = ne1 / 1;          // 300000 groups
    const int ng2 = ne2 / 2;          // 300000
    const int ng3 = ne3 / 3;          // 200000

    int* counts1 = (int*)d_ws;
    int* counts2 = counts1 + N_NODES;
    int* counts3 = counts2 + N_NODES;
    int* cursor1 = counts3 + N_NODES;
    int* cursor2 = cursor1 + N_NODES;
    int* cursor3 = cursor2 + N_NODES;
    int* sorted1 = cursor3 + N_NODES;
    int* sorted2 = sorted1 + ng1;
    int* sorted3 = sorted2 + ng2;
    float* CwT   = (float*)(sorted3 + ng3);

    hipMemsetAsync(d_ws, 0, 3 * N_NODES * sizeof(int), stream);
    transpose_cw_kernel<<<DIM, DIM, 0, stream>>>(Cw, CwT);
    count_kernel<<<(ng1 + 255) / 256, 256, 0, stream>>>(e1 + ne1, ng1, 1, counts1);
    count_kernel<<<(ng2 + 255) / 256, 256, 0, stream>>>(e2 + ne2, ng2, 2, counts2);
    count_kernel<<<(ng3 + 255) / 256, 256, 0, stream>>>(e3 + ne3, ng3, 3, counts3);
    scan_kernel<<<1, 1024, 0, stream>>>(counts1, cursor1, N_NODES);
    scan_kernel<<<1, 1024, 0, stream>>>(counts2, cursor2, N_NODES);
    scan_kernel<<<1, 1024, 0, stream>>>(counts3, cursor3, N_NODES);
    scatter_kernel<<<(ng1 + 255) / 256, 256, 0, stream>>>(e1 + ne1, cursor1, sorted1, ng1, 1);
    scatter_kernel<<<(ng2 + 255) / 256, 256, 0, stream>>>(e2 + ne2, cursor2, sorted2, ng2, 2);
    scatter_kernel<<<(ng3 + 255) / 256, 256, 0, stream>>>(e3 + ne3, cursor3, sorted3, ng3, 3);

    // dense: out = x @ Cw^T + Cb  (writes every row -> initializes d_out)
    hgnn_mm_kernel<1, 1><<<(N_NODES + 127) / 128, 256, 0, stream>>>(
        x, nullptr, nullptr, nullptr, CwT, nullptr, Cb, out, N_NODES);
    // edge types: sorted-by-dest, segmented atomic epilogue
    hgnn_mm_kernel<1, 0><<<(ng1 + 127) / 128, 256, 0, stream>>>(
        x, e1, e1 + ne1, sorted1, A1, counts1, nullptr, out, ng1);
    hgnn_mm_kernel<2, 0><<<(ng2 + 127) / 128, 256, 0, stream>>>(
        x, e2, e2 + ne2, sorted2, A2, counts2, nullptr, out, ng2);
    hgnn_mm_kernel<3, 0><<<(ng3 + 127) / 128, 256, 0, stream>>>(
        x, e3, e3 + ne3, sorted3, A3, counts3, nullptr, out, ng3);
}

// Round 3
// 355.898 us; speedup vs baseline: 8.5077x; 3.0253x over previous
//
#include <hip/hip_runtime.h>

#define N_NODES 100000
#define DIM 128

typedef __attribute__((ext_vector_type(8))) short bf16x8;
typedef __attribute__((ext_vector_type(4))) float f32x4;
typedef __attribute__((ext_vector_type(8))) unsigned short ushort8;

__device__ __forceinline__ unsigned short f2bf(float f) {
    union { float f; unsigned u; } v; v.f = f;
    unsigned u = v.u + 0x7FFFu + ((v.u >> 16) & 1u);
    return (unsigned short)(u >> 16);
}

__device__ __forceinline__ void gload_lds16(const void* g, void* l) {
    __builtin_amdgcn_global_load_lds((const __attribute__((address_space(1))) void*)g,
                                     (__attribute__((address_space(3))) void*)l, 16, 0, 0);
}

// ---------------- x -> bf16 ----------------
__global__ void cvt_x_kernel(const float* __restrict__ x, unsigned short* __restrict__ xb,
                             int n8) {
    int i = blockIdx.x * 256 + threadIdx.x;
    if (i < n8) {
        const float4* p = reinterpret_cast<const float4*>(x) + (size_t)i * 2;
        float4 a = p[0], b = p[1];
        ushort8 o;
        o[0] = f2bf(a.x); o[1] = f2bf(a.y); o[2] = f2bf(a.z); o[3] = f2bf(a.w);
        o[4] = f2bf(b.x); o[5] = f2bf(b.y); o[6] = f2bf(b.z); o[7] = f2bf(b.w);
        *reinterpret_cast<ushort8*>(xb + (size_t)i * 8) = o;
    }
}

// ---------------- A[k][c] -> BT[c][k] bf16 (or no transpose for Cw) -------------
__global__ void cvt_B_kernel(const float* __restrict__ in, unsigned short* __restrict__ outp,
                             int K, int transpose) {
    int c = blockIdx.y;                         // 0..127
    int k = blockIdx.x * 128 + threadIdx.x;
    if (k < K)
        outp[(size_t)c * K + k] =
            f2bf(transpose ? in[(size_t)k * 128 + c] : in[(size_t)c * K + k]);
}

// ---------------- counts ----------------
__global__ void count_kernel(const int* __restrict__ idx1, int ngroups, int arity,
                             int* __restrict__ counts) {
    int g = blockIdx.x * 256 + threadIdx.x;
    if (g < ngroups) atomicAdd(&counts[idx1[(size_t)g * arity]], 1);
}

// ---------------- hierarchical scan: pass1 block sums ----------------
__global__ __launch_bounds__(256) void scan_p1(const int* __restrict__ counts,
                                               int* __restrict__ partials) {
    __shared__ int red[256];
    int type = blockIdx.y, blk = blockIdx.x, tid = threadIdx.x;
    int base = blk * 4096 + tid * 16;
    int s = 0;
#pragma unroll
    for (int j = 0; j < 16; ++j) {
        int i = base + j;
        s += (i < N_NODES) ? counts[(size_t)type * N_NODES + i] : 0;
    }
    red[tid] = s;
    __syncthreads();
    for (int off = 128; off > 0; off >>= 1) {
        if (tid < off) red[tid] += red[tid + off];
        __syncthreads();
    }
    if (tid == 0) partials[type * 32 + blk] = red[0];
}

// ---------------- pass2: exclusive scan of 25 partials per type (serial) --------
__global__ void scan_p2(int* __restrict__ partials) {
    int t = threadIdx.x;
    if (t < 3) {
        int run = 0;
        for (int b = 0; b < 25; ++b) {
            int v = partials[t * 32 + b];
            partials[t * 32 + b] = run;
            run += v;
        }
    }
}

// ---------------- pass3: local exclusive scan + offset -> cursor ----------------
__global__ __launch_bounds__(256) void scan_p3(const int* __restrict__ counts,
                                               const int* __restrict__ partials,
                                               int* __restrict__ cursor) {
    __shared__ int tsum[256];
    int type = blockIdx.y, blk = blockIdx.x, tid = threadIdx.x;
    int base = blk * 4096 + tid * 16;
    int v[16];
    int s = 0;
#pragma unroll
    for (int j = 0; j < 16; ++j) {
        int i = base + j;
        v[j] = (i < N_NODES) ? counts[(size_t)type * N_NODES + i] : 0;
        s += v[j];
    }
    tsum[tid] = s;
    __syncthreads();
    for (int off = 1; off < 256; off <<= 1) {
        int t2 = (tid >= off) ? tsum[tid - off] : 0;
        __syncthreads();
        tsum[tid] += t2;
        __syncthreads();
    }
    int run = tsum[tid] - s + partials[type * 32 + blk];
#pragma unroll
    for (int j = 0; j < 16; ++j) {
        int i = base + j;
        if (i < N_NODES) cursor[(size_t)type * N_NODES + i] = run;
        run += v[j];
    }
}

// ---------------- counting-sort scatter ----------------
__global__ void scatter_kernel(const int* __restrict__ idx1, int* __restrict__ cursor,
                               int* __restrict__ sorted, int ngroups, int arity) {
    int g = blockIdx.x * 256 + threadIdx.x;
    if (g < ngroups) {
        int d = idx1[(size_t)g * arity];
        int pos = atomicAdd(&cursor[d], 1);
        sorted[pos] = g;
    }
}

// ---------------- MFMA GEMM (gather + scatter fused) ----------------
// LDS byte map:  [0,16384)  S double-buffer (2 x 8192)
//                [16384,32768) BT double-buffer
//                [32768,34304) nodebuf int[3][128]
//                [34304,34816) destbuf int[128]
//                [34816,35328) invbuf float[128]
// Epilogue reuses [0,16896) as float Ep[32][132].
template <int ARITY, int MODE>
__global__ __launch_bounds__(256, 2) void hgnn_mfma_kernel(
    const unsigned short* __restrict__ xb,   // [N_NODES][128] bf16
    const int* __restrict__ idx0,
    const int* __restrict__ idx1,
    const int* __restrict__ sorted,
    const unsigned short* __restrict__ BT,   // [128][K] bf16
    const int* __restrict__ counts,
    const float* __restrict__ bias,
    float* __restrict__ out,
    int ngroups)
{
    constexpr int K = 128 * ARITY;
    constexpr int NSTEPS = 4 * ARITY;
    constexpr int SOFF = 0, TOFF = 16384, NOFF = 32768, DOFF = 34304, IOFF = 34816;

    __shared__ __align__(16) char smem[35328];
    int* nodebuf = (int*)(smem + NOFF);
    int* destbuf = (int*)(smem + DOFF);
    float* invbuf = (float*)(smem + IOFF);

    const int tid = threadIdx.x;
    const int w = tid >> 6, l = tid & 63;
    const int g0 = blockIdx.x * 128;
    const int lrow = l & 15, lk = l >> 4;
    const int wr = (w & 1) * 64, wc = (w >> 1) * 64;

    if (MODE == 0) {
        if (tid < 128) {
            int g = g0 + tid;
            int sg = (g < ngroups) ? sorted[g] : 0;
            int d = (g < ngroups) ? idx1[(size_t)sg * ARITY] : -1;
            destbuf[tid] = d;
            invbuf[tid] = (g < ngroups) ? (1.0f / (float)counts[d]) : 0.f;
#pragma unroll
            for (int a = 0; a < ARITY; ++a)
                nodebuf[a * 128 + tid] = (g < ngroups) ? idx0[(size_t)sg * ARITY + a] : 0;
        }
        __syncthreads();
    }

    // per-lane staging constants (inverse of the read-side XOR swizzle)
    const int q = (((l & 7) ^ (l >> 3)) << 4);  // b'
    const int inner = q & 63;                   // byte offset within the 64B row-chunk
    const int rpq = ((l >> 3) << 1) + (q >> 6); // row within a 16-row unit

    // fragment read offsets (XOR-swizzled)
    int aoff[4], boff[4];
#pragma unroll
    for (int mi = 0; mi < 4; ++mi) {
        int r = wr + mi * 16 + lrow;
        int P = r >> 1;
        aoff[mi] = P * 128 + ((((r & 1) << 6) | (lk << 4)) ^ ((P & 7) << 4));
        int c = wc + mi * 16 + lrow;
        int Pc = c >> 1;
        boff[mi] = Pc * 128 + ((((c & 1) << 6) | (lk << 4)) ^ ((Pc & 7) << 4));
    }

    f32x4 acc[4][4];
#pragma unroll
    for (int mi = 0; mi < 4; ++mi)
#pragma unroll
        for (int ni = 0; ni < 4; ++ni) acc[mi][ni] = (f32x4){0.f, 0.f, 0.f, 0.f};

    auto STAGE = [&](int kc, int buf) {
        const int a = (kc * 32) >> 7;
        const int f0b = ((kc * 32) & 127) * 2;
#pragma unroll
        for (int i = 0; i < 2; ++i) {
            int u = w * 2 + i;
            int r = u * 16 + rpq;
            int node;
            if (MODE == 1) {
                int gg = g0 + r;
                node = (gg < ngroups) ? gg : 0;
            } else {
                node = nodebuf[a * 128 + r];
            }
            gload_lds16((const char*)xb + (size_t)node * 256 + f0b + inner,
                        smem + SOFF + buf * 8192 + u * 1024);
            gload_lds16((const char*)BT + (size_t)r * (K * 2) + kc * 64 + inner,
                        smem + TOFF + buf * 8192 + u * 1024);
        }
    };

    STAGE(0, 0);
    __syncthreads();

    for (int t = 0; t < NSTEPS; ++t) {
        const int buf = t & 1;
        if (t + 1 < NSTEPS) STAGE(t + 1, buf ^ 1);
        bf16x8 af[4], bg[4];
#pragma unroll
        for (int mi = 0; mi < 4; ++mi)
            af[mi] = *reinterpret_cast<const bf16x8*>(smem + SOFF + buf * 8192 + aoff[mi]);
#pragma unroll
        for (int ni = 0; ni < 4; ++ni)
            bg[ni] = *reinterpret_cast<const bf16x8*>(smem + TOFF + buf * 8192 + boff[ni]);
#pragma unroll
        for (int mi = 0; mi < 4; ++mi)
#pragma unroll
            for (int ni = 0; ni < 4; ++ni)
                acc[mi][ni] = __builtin_amdgcn_mfma_f32_16x16x32_bf16(
                    af[mi], bg[ni], acc[mi][ni], 0, 0, 0);
        __syncthreads();
    }

    if (MODE == 1) {
        float bv[4];
#pragma unroll
        for (int ni = 0; ni < 4; ++ni) bv[ni] = bias[wc + ni * 16 + lrow];
#pragma unroll
        for (int mi = 0; mi < 4; ++mi) {
#pragma unroll
            for (int reg = 0; reg < 4; ++reg) {
                int g = g0 + wr + mi * 16 + lk * 4 + reg;
                if (g < ngroups) {
#pragma unroll
                    for (int ni = 0; ni < 4; ++ni)
                        out[(size_t)g * DIM + wc + ni * 16 + lrow] = acc[mi][ni][reg] + bv[ni];
                }
            }
        }
    } else {
        float* Ep = (float*)smem;  // [32][132]
#pragma unroll
        for (int c0 = 0; c0 < 128; c0 += 32) {
            if ((w & 1) == (c0 >> 6)) {
                constexpr int dummy = 0; (void)dummy;
                const int m0 = (c0 & 63) >> 4;
#pragma unroll
                for (int mm = 0; mm < 2; ++mm) {
                    const int mi = m0 + mm;
                    const int lr = mm * 16 + lk * 4;
#pragma unroll
                    for (int ni = 0; ni < 4; ++ni) {
                        const int col = wc + ni * 16 + lrow;
#pragma unroll
                        for (int reg = 0; reg < 4; ++reg)
                            Ep[(lr + reg) * 132 + col] = acc[mi][ni][reg];
                    }
                }
            }
            __syncthreads();
            int cur = -1;
            float r0 = 0.f, r1 = 0.f;
#pragma unroll
            for (int r = 0; r < 8; ++r) {
                int row = w * 8 + r;
                int g = g0 + c0 + row;
                if (g < ngroups) {
                    int d = destbuf[c0 + row];
                    float inv = invbuf[c0 + row];
                    if (d != cur) {
                        if (cur >= 0) {
                            float* op = out + (size_t)cur * DIM;
                            __hip_atomic_fetch_add(&op[l], r0, __ATOMIC_RELAXED,
                                                   __HIP_MEMORY_SCOPE_AGENT);
                            __hip_atomic_fetch_add(&op[l + 64], r1, __ATOMIC_RELAXED,
                                                   __HIP_MEMORY_SCOPE_AGENT);
                        }
                        cur = d;
                        r0 = 0.f;
                        r1 = 0.f;
                    }
                    r0 += Ep[row * 132 + l] * inv;
                    r1 += Ep[row * 132 + 64 + l] * inv;
                }
            }
            if (cur >= 0) {
                float* op = out + (size_t)cur * DIM;
                __hip_atomic_fetch_add(&op[l], r0, __ATOMIC_RELAXED,
                                       __HIP_MEMORY_SCOPE_AGENT);
                __hip_atomic_fetch_add(&op[l + 64], r1, __ATOMIC_RELAXED,
                                       __HIP_MEMORY_SCOPE_AGENT);
            }
            __syncthreads();
        }
    }
}

extern "C" void kernel_launch(void* const* d_in, const int* in_sizes, int n_in,
                              void* d_out, int out_size, void* d_ws, size_t ws_size,
                              hipStream_t stream) {
    const float* x  = (const float*)d_in[0];
    const int*   e1 = (const int*)d_in[1];
    const int*   e2 = (const int*)d_in[2];
    const int*   e3 = (const int*)d_in[3];
    const float* A1 = (const float*)d_in[4];
    const float* A2 = (const float*)d_in[5];
    const float* A3 = (const float*)d_in[6];
    const float* Cw = (const float*)d_in[7];
    const float* Cb = (const float*)d_in[8];
    float* out = (float*)d_out;

    const int ne1 = in_sizes[1] / 2, ne2 = in_sizes[2] / 2, ne3 = in_sizes[3] / 2;
    const int ng1 = ne1, ng2 = ne2 / 2, ng3 = ne3 / 3;
    const int N = N_NODES;

    int* counts  = (int*)d_ws;          // 3*N
    int* cursor  = counts + 3 * N;      // 3*N
    int* sorted1 = cursor + 3 * N;
    int* sorted2 = sorted1 + ng1;
    int* sorted3 = sorted2 + ng2;
    int* partials = sorted3 + ng3;      // 96 used, pad 128
    unsigned short* bt1 = (unsigned short*)(partials + 128);
    unsigned short* bt2 = bt1 + 128 * 128;
    unsigned short* bt3 = bt2 + 128 * 256;
    unsigned short* cwb = bt3 + 128 * 384;
    unsigned short* xb  = cwb + 128 * 128;

    hipMemsetAsync(counts, 0, (size_t)3 * N * sizeof(int), stream);
    cvt_x_kernel<<<(N * DIM / 8 + 255) / 256, 256, 0, stream>>>(x, xb, N * DIM / 8);
    cvt_B_kernel<<<dim3(1, 128), 128, 0, stream>>>(A1, bt1, 128, 1);
    cvt_B_kernel<<<dim3(2, 128), 128, 0, stream>>>(A2, bt2, 256, 1);
    cvt_B_kernel<<<dim3(3, 128), 128, 0, stream>>>(A3, bt3, 384, 1);
    cvt_B_kernel<<<dim3(1, 128), 128, 0, stream>>>(Cw, cwb, 128, 0);

    count_kernel<<<(ng1 + 255) / 256, 256, 0, stream>>>(e1 + ne1, ng1, 1, counts);
    count_kernel<<<(ng2 + 255) / 256, 256, 0, stream>>>(e2 + ne2, ng2, 2, counts + N);
    count_kernel<<<(ng3 + 255) / 256, 256, 0, stream>>>(e3 + ne3, ng3, 3, counts + 2 * N);
    scan_p1<<<dim3(25, 3), 256, 0, stream>>>(counts, partials);
    scan_p2<<<1, 64, 0, stream>>>(partials);
    scan_p3<<<dim3(25, 3), 256, 0, stream>>>(counts, partials, cursor);
    scatter_kernel<<<(ng1 + 255) / 256, 256, 0, stream>>>(e1 + ne1, cursor, sorted1, ng1, 1);
    scatter_kernel<<<(ng2 + 255) / 256, 256, 0, stream>>>(e2 + ne2, cursor + N, sorted2, ng2, 2);
    scatter_kernel<<<(ng3 + 255) / 256, 256, 0, stream>>>(e3 + ne3, cursor + 2 * N, sorted3, ng3, 3);

    // dense first (initializes every out row), then edge kernels atomically add
    hgnn_mfma_kernel<1, 1><<<(N + 127) / 128, 256, 0, stream>>>(
        xb, nullptr, nullptr, nullptr, cwb, nullptr, Cb, out, N);
    hgnn_mfma_kernel<1, 0><<<(ng1 + 127) / 128, 256, 0, stream>>>(
        xb, e1, e1 + ne1, sorted1, bt1, counts, nullptr, out, ng1);
    hgnn_mfma_kernel<2, 0><<<(ng2 + 127) / 128, 256, 0, stream>>>(
        xb, e2, e2 + ne2, sorted2, bt2, counts + N, nullptr, out, ng2);
    hgnn_mfma_kernel<3, 0><<<(ng3 + 127) / 128, 256, 0, stream>>>(
        xb, e3, e3 + ne3, sorted3, bt3, counts + 2 * N, nullptr, out, ng3);
}